// Round 1
// baseline (2954.759 us; speedup 1.0000x reference)
//
#include <hip/hip_runtime.h>

// Problem constants (HyperScatteringModule): V=65536, E=16384, NNZ=1048576, F=128
#define FEAT 128

// ---------------- CSR build ----------------

__global__ void count_deg(const int* __restrict__ vids, const int* __restrict__ eids,
                          int* __restrict__ deg_v, int* __restrict__ deg_e, int nnz) {
    int n = blockIdx.x * blockDim.x + threadIdx.x;
    if (n < nnz) {
        atomicAdd(&deg_v[vids[n]], 1);
        atomicAdd(&deg_e[eids[n]], 1);
    }
}

// Single-block exclusive scan over N degrees; writes offsets, cursor copy, and 1/deg.
template <int N, int T>
__global__ __launch_bounds__(T) void scan_excl(const int* __restrict__ deg,
                                               int* __restrict__ off,
                                               int* __restrict__ cur,
                                               float* __restrict__ inv) {
    __shared__ int partial[T];
    const int per = N / T;
    int tid = threadIdx.x;
    int base = tid * per;
    int s = 0;
    for (int i = 0; i < per; ++i) s += deg[base + i];
    partial[tid] = s;
    __syncthreads();
    // Hillis-Steele inclusive scan over the T partials
    for (int d = 1; d < T; d <<= 1) {
        int add = (tid >= d) ? partial[tid - d] : 0;
        __syncthreads();
        partial[tid] += add;
        __syncthreads();
    }
    int run = (tid > 0) ? partial[tid - 1] : 0;
    for (int i = 0; i < per; ++i) {
        int d = deg[base + i];
        off[base + i] = run;
        cur[base + i] = run;
        inv[base + i] = (d > 0) ? (1.0f / (float)d) : 0.0f;
        run += d;
    }
    if (tid == T - 1) off[N] = run;
}

__global__ void fill_csr(const int* __restrict__ vids, const int* __restrict__ eids,
                         int* __restrict__ cur_v, int* __restrict__ cur_e,
                         int* __restrict__ v_nbr_e, int* __restrict__ e_nbr_v, int nnz) {
    int n = blockIdx.x * blockDim.x + threadIdx.x;
    if (n < nnz) {
        int v = vids[n], e = eids[n];
        int p = atomicAdd(&cur_e[e], 1);
        e_nbr_v[p] = v;
        int q = atomicAdd(&cur_v[v], 1);
        v_nbr_e[q] = e;
    }
}

// ---------------- Diffusion step: segment gather-sum ----------------
// One 64-lane wave per segment; each lane owns 2 features (float2).
// dst[seg][:] = sum_{u in nbr[off[seg]:off[seg+1]]} src[u][:] * wgt[u]
__global__ __launch_bounds__(256) void gather_rows(const float* __restrict__ src, long sstride,
                                                   const int* __restrict__ offs,
                                                   const int* __restrict__ nbr,
                                                   const float* __restrict__ wgt,
                                                   float* __restrict__ dst, long dstride,
                                                   int nseg) {
    int seg = blockIdx.x * 4 + (threadIdx.x >> 6);
    if (seg >= nseg) return;
    int lane = threadIdx.x & 63;
    int s = offs[seg], t = offs[seg + 1];
    float ax = 0.f, ay = 0.f;
    int i = s;
    for (; i + 1 < t; i += 2) {
        int u0 = nbr[i], u1 = nbr[i + 1];
        float w0 = wgt[u0], w1 = wgt[u1];
        const float2 r0 = *(const float2*)(src + (long)u0 * sstride + 2 * lane);
        const float2 r1 = *(const float2*)(src + (long)u1 * sstride + 2 * lane);
        ax += r0.x * w0 + r1.x * w1;
        ay += r0.y * w0 + r1.y * w1;
    }
    if (i < t) {
        int u0 = nbr[i];
        float w0 = wgt[u0];
        const float2 r0 = *(const float2*)(src + (long)u0 * sstride + 2 * lane);
        ax += r0.x * w0;
        ay += r0.y * w0;
    }
    float2 o;
    o.x = ax;
    o.y = ay;
    *(float2*)(dst + (long)seg * dstride + 2 * lane) = o;
}

// ---------------- Final wavelet combine + relu split ----------------
// out layout: [V, 6, 256]; levels 1,2,4,8,16 were written at out[v, slot, 0:128]
// (slot=1..5); L0 is X. Per-thread read-before-write, disjoint addresses -> in-place safe.
__global__ __launch_bounds__(128) void wavelet_out(const float* __restrict__ X,
                                                   float* __restrict__ out) {
    long v = blockIdx.x;
    int f = threadIdx.x;
    float* row = out + v * 1536;
    float L0 = X[v * FEAT + f];
    float L1 = row[1 * 256 + f];
    float L2 = row[2 * 256 + f];
    float L4 = row[3 * 256 + f];
    float L8 = row[4 * 256 + f];
    float L16 = row[5 * 256 + f];
    float w[6];
    w[0] = L0 - L1;
    w[1] = L1 - L2;
    w[2] = L2 - L4;
    w[3] = L4 - L8;
    w[4] = L8 - L16;
    w[5] = L16;
#pragma unroll
    for (int r = 0; r < 6; ++r) {
        row[r * 256 + f] = fmaxf(w[r], 0.f);
        row[r * 256 + 128 + f] = fmaxf(-w[r], 0.f);
    }
}

// ---------------- launch ----------------

extern "C" void kernel_launch(void* const* d_in, const int* in_sizes, int n_in,
                              void* d_out, int out_size, void* d_ws, size_t ws_size,
                              hipStream_t stream) {
    const float* X = (const float*)d_in[0];
    const int* vids = (const int*)d_in[1];
    const int* eids = (const int*)d_in[2];
    const int NNZ = in_sizes[1];            // 1048576
    const int V = in_sizes[0] / FEAT;       // 65536
    const int E = 16384;                    // num_e (python scalar input; fixed)
    float* out = (float*)d_out;

    // workspace layout (~17.3 MB)
    char* w = (char*)d_ws;
    size_t o = 0;
    auto take = [&](size_t bytes) {
        void* p = (void*)(w + o);
        o = (o + bytes + 255) & ~(size_t)255;
        return p;
    };
    int* deg_v = (int*)take((size_t)(V + E) * 4);   // deg_v and deg_e contiguous
    int* deg_e = deg_v + V;
    int* off_e = (int*)take((size_t)(E + 1) * 4);
    int* off_v = (int*)take((size_t)(V + 1) * 4);
    int* cur_e = (int*)take((size_t)E * 4);
    int* cur_v = (int*)take((size_t)V * 4);
    float* inv_e = (float*)take((size_t)E * 4);
    float* inv_v = (float*)take((size_t)V * 4);
    int* e_nbr_v = (int*)take((size_t)NNZ * 4);
    int* v_nbr_e = (int*)take((size_t)NNZ * 4);
    float* edge_feat = (float*)take((size_t)E * FEAT * 4);
    (void)ws_size;
    (void)n_in;
    (void)out_size;

    // 1) degrees
    hipMemsetAsync(deg_v, 0, (size_t)(V + E) * 4, stream);
    count_deg<<<(NNZ + 255) / 256, 256, 0, stream>>>(vids, eids, deg_v, deg_e, NNZ);

    // 2) offsets + cursors + inverse degrees
    scan_excl<16384, 1024><<<1, 1024, 0, stream>>>(deg_e, off_e, cur_e, inv_e);
    scan_excl<65536, 1024><<<1, 1024, 0, stream>>>(deg_v, off_v, cur_v, inv_v);

    // 3) adjacency lists
    fill_csr<<<(NNZ + 255) / 256, 256, 0, stream>>>(vids, eids, cur_v, cur_e, v_nbr_e, e_nbr_v, NNZ);

    // 4) 16 diffusion steps. Checkpoint levels {1,2,4,8,16} go straight into
    //    out[:, slot, 0:128] (slot 1..5); other steps ping-pong through the
    //    unused upper halves of out slots 0 and 1.
    float* tmpA = out + 128;  // out[:, 0, 128:256], row stride 1536
    float* tmpB = out + 384;  // out[:, 1, 128:256]
    const float* cin = X;
    long instride = FEAT;
    int toggle = 0;
    for (int k = 1; k <= 16; ++k) {
        gather_rows<<<E / 4, 256, 0, stream>>>(cin, instride, off_e, e_nbr_v, inv_v,
                                               edge_feat, FEAT, E);
        float* optr;
        if (k == 1 || k == 2 || k == 4 || k == 8 || k == 16) {
            int slot = (k == 1) ? 1 : (k == 2) ? 2 : (k == 4) ? 3 : (k == 8) ? 4 : 5;
            optr = out + slot * 256;
        } else {
            optr = toggle ? tmpB : tmpA;
            toggle ^= 1;
        }
        gather_rows<<<V / 4, 256, 0, stream>>>(edge_feat, FEAT, off_v, v_nbr_e, inv_e,
                                               optr, 1536, V);
        cin = optr;
        instride = 1536;
    }

    // 5) wavelet combine + relu split, in place over out
    wavelet_out<<<V, 128, 0, stream>>>(X, out);
}

// Round 2
// 1674.081 us; speedup vs baseline: 1.7650x; 1.7650x over previous
//
#include <hip/hip_runtime.h>

// HyperScatteringModule: V=65536, E=16384, NNZ=1048576, F=128
#define FEAT 128

// ---------------- helpers ----------------

__device__ inline unsigned pack_bf2(float a, float b) {
    // round-to-nearest-even bf16 pack: lo=a, hi=b
    unsigned ua = __float_as_uint(a);
    unsigned ub = __float_as_uint(b);
    unsigned ra = (ua + 0x7FFFu + ((ua >> 16) & 1u)) >> 16;
    unsigned rb = (ub + 0x7FFFu + ((ub >> 16) & 1u)) >> 16;
    return ra | (rb << 16);
}

// ---------------- CSR build ----------------

__global__ void count_deg(const int* __restrict__ vids, const int* __restrict__ eids,
                          int* __restrict__ deg_v, int* __restrict__ deg_e, int nnz) {
    int n = blockIdx.x * blockDim.x + threadIdx.x;
    if (n < nnz) {
        atomicAdd(&deg_v[vids[n]], 1);
        atomicAdd(&deg_e[eids[n]], 1);
    }
}

template <int N, int T>
__global__ __launch_bounds__(T) void scan_excl(const int* __restrict__ deg,
                                               int* __restrict__ off,
                                               int* __restrict__ cur,
                                               float* __restrict__ inv) {
    __shared__ int partial[T];
    const int per = N / T;
    int tid = threadIdx.x;
    int base = tid * per;
    int s = 0;
    for (int i = 0; i < per; ++i) s += deg[base + i];
    partial[tid] = s;
    __syncthreads();
    for (int d = 1; d < T; d <<= 1) {
        int add = (tid >= d) ? partial[tid - d] : 0;
        __syncthreads();
        partial[tid] += add;
        __syncthreads();
    }
    int run = (tid > 0) ? partial[tid - 1] : 0;
    for (int i = 0; i < per; ++i) {
        int d = deg[base + i];
        off[base + i] = run;
        cur[base + i] = run;
        inv[base + i] = (d > 0) ? (1.0f / (float)d) : 0.0f;
        run += d;
    }
    if (tid == T - 1) off[N] = run;
}

__global__ void fill_csr(const int* __restrict__ vids, const int* __restrict__ eids,
                         int* __restrict__ cur_v, int* __restrict__ cur_e,
                         int* __restrict__ v_nbr_e, int* __restrict__ e_nbr_v, int nnz) {
    int n = blockIdx.x * blockDim.x + threadIdx.x;
    if (n < nnz) {
        int v = vids[n], e = eids[n];
        int p = atomicAdd(&cur_e[e], 1);
        e_nbr_v[p] = v;
        int q = atomicAdd(&cur_v[v], 1);
        v_nbr_e[q] = e;
    }
}

// ---------------- prescale: xs = bf16(X * inv_v) ----------------
__global__ __launch_bounds__(256) void prescale(const float* __restrict__ X,
                                                const float* __restrict__ inv_v,
                                                unsigned* __restrict__ xs) {
    int i = blockIdx.x * 256 + threadIdx.x;  // dword index over V*64
    float sc = inv_v[i >> 6];
    float2 x = *(const float2*)(X + 2 * (long)i);
    xs[i] = pack_bf2(x.x * sc, x.y * sc);
}

// ---------------- unweighted segment gather-sum over bf16 rows ----------------
// One 64-lane wave per segment; lane owns 2 feats (one packed dword per row).
// acc = sum_{u in nbr[off[seg]:off[seg+1]]} src[u][:]
// dst_bf[seg] = bf16(acc * scale[seg]);  optional dst_f32[seg] = acc (stride 1536)
__global__ __launch_bounds__(256) void gather_bf(const unsigned* __restrict__ src,
                                                 const int* __restrict__ offs,
                                                 const int* __restrict__ nbr,
                                                 const float* __restrict__ scale,
                                                 unsigned* __restrict__ dst_bf,
                                                 float* __restrict__ dst_f32,
                                                 int nseg) {
    int seg = blockIdx.x * 4 + (threadIdx.x >> 6);
    if (seg >= nseg) return;
    int lane = threadIdx.x & 63;
    int s = offs[seg], t = offs[seg + 1];
    float ax = 0.f, ay = 0.f;
    for (int base = s; base < t; base += 64) {
        int n = t - base;
        if (n > 64) n = 64;
        int myidx = nbr[base + (lane < n ? lane : 0)];
        int j = 0;
        for (; j + 4 <= n; j += 4) {
            int u0 = __shfl(myidx, j, 64);
            int u1 = __shfl(myidx, j + 1, 64);
            int u2 = __shfl(myidx, j + 2, 64);
            int u3 = __shfl(myidx, j + 3, 64);
            unsigned r0 = src[(long)u0 * 64 + lane];
            unsigned r1 = src[(long)u1 * 64 + lane];
            unsigned r2 = src[(long)u2 * 64 + lane];
            unsigned r3 = src[(long)u3 * 64 + lane];
            ax += __uint_as_float(r0 << 16);
            ay += __uint_as_float(r0 & 0xFFFF0000u);
            ax += __uint_as_float(r1 << 16);
            ay += __uint_as_float(r1 & 0xFFFF0000u);
            ax += __uint_as_float(r2 << 16);
            ay += __uint_as_float(r2 & 0xFFFF0000u);
            ax += __uint_as_float(r3 << 16);
            ay += __uint_as_float(r3 & 0xFFFF0000u);
        }
        for (; j < n; ++j) {
            int u = __shfl(myidx, j, 64);
            unsigned r = src[(long)u * 64 + lane];
            ax += __uint_as_float(r << 16);
            ay += __uint_as_float(r & 0xFFFF0000u);
        }
    }
    float sc = scale[seg];
    dst_bf[(long)seg * 64 + lane] = pack_bf2(ax * sc, ay * sc);
    if (dst_f32) {
        float2 o;
        o.x = ax;
        o.y = ay;
        *(float2*)(dst_f32 + (long)seg * 1536 + 2 * lane) = o;
    }
}

// ---------------- final wavelet combine + relu split (float4) ----------------
// out layout [V, 6, 256]; checkpoints (unscaled fp32) sit at out[v, slot, 0:128].
__global__ __launch_bounds__(256) void wavelet_out(const float* __restrict__ X,
                                                   float* __restrict__ out) {
    int tid = blockIdx.x * 256 + threadIdx.x;  // V*32 threads, 4 feats each
    int v = tid >> 5;
    int f4 = (tid & 31) * 4;
    float* row = out + (long)v * 1536;
    float4 L0 = *(const float4*)(X + (long)v * FEAT + f4);
    float4 L1 = *(const float4*)(row + 1 * 256 + f4);
    float4 L2 = *(const float4*)(row + 2 * 256 + f4);
    float4 L4 = *(const float4*)(row + 3 * 256 + f4);
    float4 L8 = *(const float4*)(row + 4 * 256 + f4);
    float4 L16 = *(const float4*)(row + 5 * 256 + f4);
    float4 w[6];
    w[0] = make_float4(L0.x - L1.x, L0.y - L1.y, L0.z - L1.z, L0.w - L1.w);
    w[1] = make_float4(L1.x - L2.x, L1.y - L2.y, L1.z - L2.z, L1.w - L2.w);
    w[2] = make_float4(L2.x - L4.x, L2.y - L4.y, L2.z - L4.z, L2.w - L4.w);
    w[3] = make_float4(L4.x - L8.x, L4.y - L8.y, L4.z - L8.z, L4.w - L8.w);
    w[4] = make_float4(L8.x - L16.x, L8.y - L16.y, L8.z - L16.z, L8.w - L16.w);
    w[5] = L16;
#pragma unroll
    for (int r = 0; r < 6; ++r) {
        float4 p, m;
        p.x = fmaxf(w[r].x, 0.f); m.x = fmaxf(-w[r].x, 0.f);
        p.y = fmaxf(w[r].y, 0.f); m.y = fmaxf(-w[r].y, 0.f);
        p.z = fmaxf(w[r].z, 0.f); m.z = fmaxf(-w[r].z, 0.f);
        p.w = fmaxf(w[r].w, 0.f); m.w = fmaxf(-w[r].w, 0.f);
        *(float4*)(row + r * 256 + f4) = p;
        *(float4*)(row + r * 256 + 128 + f4) = m;
    }
}

// ---------------- launch ----------------

extern "C" void kernel_launch(void* const* d_in, const int* in_sizes, int n_in,
                              void* d_out, int out_size, void* d_ws, size_t ws_size,
                              hipStream_t stream) {
    const float* X = (const float*)d_in[0];
    const int* vids = (const int*)d_in[1];
    const int* eids = (const int*)d_in[2];
    const int NNZ = in_sizes[1];         // 1048576
    const int V = in_sizes[0] / FEAT;    // 65536
    const int E = 16384;                 // num_e
    float* out = (float*)d_out;

    char* w = (char*)d_ws;
    size_t o = 0;
    auto take = [&](size_t bytes) {
        void* p = (void*)(w + o);
        o = (o + bytes + 255) & ~(size_t)255;
        return p;
    };
    int* deg_v = (int*)take((size_t)(V + E) * 4);  // deg_v, deg_e contiguous
    int* deg_e = deg_v + V;
    int* off_e = (int*)take((size_t)(E + 1) * 4);
    int* off_v = (int*)take((size_t)(V + 1) * 4);
    int* cur_e = (int*)take((size_t)E * 4);
    int* cur_v = (int*)take((size_t)V * 4);
    float* inv_e = (float*)take((size_t)E * 4);
    float* inv_v = (float*)take((size_t)V * 4);
    int* e_nbr_v = (int*)take((size_t)NNZ * 4);
    int* v_nbr_e = (int*)take((size_t)NNZ * 4);
    unsigned* xs = (unsigned*)take((size_t)V * 64 * 4);  // bf16x2 [V][64]
    unsigned* es = (unsigned*)take((size_t)E * 64 * 4);  // bf16x2 [E][64]
    (void)ws_size;
    (void)n_in;
    (void)out_size;

    // 1) degrees
    hipMemsetAsync(deg_v, 0, (size_t)(V + E) * 4, stream);
    count_deg<<<(NNZ + 255) / 256, 256, 0, stream>>>(vids, eids, deg_v, deg_e, NNZ);

    // 2) offsets + cursors + inverse degrees
    scan_excl<16384, 1024><<<1, 1024, 0, stream>>>(deg_e, off_e, cur_e, inv_e);
    scan_excl<65536, 1024><<<1, 1024, 0, stream>>>(deg_v, off_v, cur_v, inv_v);

    // 3) adjacency lists
    fill_csr<<<(NNZ + 255) / 256, 256, 0, stream>>>(vids, eids, cur_v, cur_e, v_nbr_e, e_nbr_v, NNZ);

    // 4) xs = bf16(X * inv_v)
    prescale<<<V * 64 / 256, 256, 0, stream>>>(X, inv_v, xs);

    // 5) 16 diffusion steps, weights folded into stored values:
    //    v2e: es[e] = bf16(inv_e[e] * sum_{v in e} xs[v])         (acc = edge_feat)
    //    e2v: acc = sum_{e ni v} es[e] = node level (unscaled);
    //         xs[v] = bf16(inv_v[v] * acc); checkpoints write acc as fp32 to out.
    for (int k = 1; k <= 16; ++k) {
        gather_bf<<<E / 4, 256, 0, stream>>>(xs, off_e, e_nbr_v, inv_e, es, nullptr, E);
        float* ckpt = nullptr;
        if (k == 1) ckpt = out + 1 * 256;
        else if (k == 2) ckpt = out + 2 * 256;
        else if (k == 4) ckpt = out + 3 * 256;
        else if (k == 8) ckpt = out + 4 * 256;
        else if (k == 16) ckpt = out + 5 * 256;
        gather_bf<<<V / 4, 256, 0, stream>>>(es, off_v, v_nbr_e, inv_v, xs, ckpt, V);
    }

    // 6) wavelet combine + relu split, in place over out
    wavelet_out<<<V * 32 / 256, 256, 0, stream>>>(X, out);
}

// Round 3
// 1375.524 us; speedup vs baseline: 2.1481x; 1.2170x over previous
//
#include <hip/hip_runtime.h>

// HyperScatteringModule: V=65536, E=16384, NNZ=1048576, F=128
#define FEAT 128

// ---------------- helpers ----------------

__device__ inline unsigned pack_bf2(float a, float b) {
    // round-to-nearest-even bf16 pack: lo=a, hi=b
    unsigned ua = __float_as_uint(a), ub = __float_as_uint(b);
    unsigned ra = (ua + 0x7FFFu + ((ua >> 16) & 1u)) >> 16;
    unsigned rb = (ub + 0x7FFFu + ((ub >> 16) & 1u)) >> 16;
    return ra | (rb << 16);
}
__device__ inline float bflo(unsigned u) { return __uint_as_float(u << 16); }
__device__ inline float bfhi(unsigned u) { return __uint_as_float(u & 0xFFFF0000u); }

// ---------------- CSR build ----------------

__global__ void count_deg(const int* __restrict__ vids, const int* __restrict__ eids,
                          int* __restrict__ deg_v, int* __restrict__ deg_e, int nnz) {
    int n = blockIdx.x * blockDim.x + threadIdx.x;
    if (n < nnz) {
        atomicAdd(&deg_v[vids[n]], 1);
        atomicAdd(&deg_e[eids[n]], 1);
    }
}

// Exclusive scan over CHUNK-padded degrees; off/cur = padded offsets, inv = 1/true_deg.
template <int N, int T, int CHUNK>
__global__ __launch_bounds__(T) void scan_pad(const int* __restrict__ deg,
                                              int* __restrict__ off,
                                              int* __restrict__ cur,
                                              float* __restrict__ inv) {
    __shared__ int partial[T];
    const int per = N / T;
    int tid = threadIdx.x;
    int base = tid * per;
    int dloc[per];
    int s = 0;
#pragma unroll
    for (int i = 0; i < per / 4; ++i) {
        int4 d4 = *(const int4*)(deg + base + 4 * i);
        dloc[4 * i] = d4.x; dloc[4 * i + 1] = d4.y;
        dloc[4 * i + 2] = d4.z; dloc[4 * i + 3] = d4.w;
        s += ((d4.x + CHUNK - 1) & ~(CHUNK - 1)) + ((d4.y + CHUNK - 1) & ~(CHUNK - 1)) +
             ((d4.z + CHUNK - 1) & ~(CHUNK - 1)) + ((d4.w + CHUNK - 1) & ~(CHUNK - 1));
    }
    partial[tid] = s;
    __syncthreads();
    for (int d = 1; d < T; d <<= 1) {
        int add = (tid >= d) ? partial[tid - d] : 0;
        __syncthreads();
        partial[tid] += add;
        __syncthreads();
    }
    int run = (tid > 0) ? partial[tid - 1] : 0;
#pragma unroll
    for (int i = 0; i < per / 4; ++i) {
        int o[4];
        float iv[4];
#pragma unroll
        for (int j = 0; j < 4; ++j) {
            int d = dloc[4 * i + j];
            o[j] = run;
            iv[j] = (d > 0) ? (1.0f / (float)d) : 0.0f;
            run += (d + CHUNK - 1) & ~(CHUNK - 1);
        }
        *(int4*)(off + base + 4 * i) = make_int4(o[0], o[1], o[2], o[3]);
        *(int4*)(cur + base + 4 * i) = make_int4(o[0], o[1], o[2], o[3]);
        *(float4*)(inv + base + 4 * i) = make_float4(iv[0], iv[1], iv[2], iv[3]);
    }
    if (tid == T - 1) off[N] = run;
}

// Fill padded slots with dummy row indices; zero the dummy rows of xs/es.
__global__ void init_pad(int* __restrict__ nbrE, int nE, int dummyE,
                         int* __restrict__ nbrV, int nV, int dummyV,
                         unsigned* __restrict__ xzero, unsigned* __restrict__ ezero) {
    int i = blockIdx.x * 256 + threadIdx.x;
    if (i < nE) nbrE[i] = dummyE;
    if (i < nV) nbrV[i] = dummyV;
    if (i < 64) { xzero[i] = 0u; ezero[i] = 0u; }
}

__global__ void fill_csr(const int* __restrict__ vids, const int* __restrict__ eids,
                         int* __restrict__ cur_v, int* __restrict__ cur_e,
                         int* __restrict__ v_nbr_e, int* __restrict__ e_nbr_v, int nnz) {
    int n = blockIdx.x * blockDim.x + threadIdx.x;
    if (n < nnz) {
        int v = vids[n], e = eids[n];
        int p = atomicAdd(&cur_e[e], 1);
        e_nbr_v[p] = v;
        int q = atomicAdd(&cur_v[v], 1);
        v_nbr_e[q] = e;
    }
}

// ---------------- prescale: xs = bf16(X * inv_v) ----------------
__global__ __launch_bounds__(256) void prescale(const float* __restrict__ X,
                                                const float* __restrict__ inv_v,
                                                unsigned* __restrict__ xs) {
    int i = blockIdx.x * 256 + threadIdx.x;  // dword index over V*64
    float sc = inv_v[i >> 6];
    float2 x = *(const float2*)(X + 2 * (long)i);
    xs[i] = pack_bf2(x.x * sc, x.y * sc);
}

// ---------------- padded segment gather-sum (scalarized indices) ----------------
// Wave handles SPW consecutive segments. Neighbor lists are CHUNK-padded with
// dummy zero-row indices, so the inner loop is branch-free. Wave id is
// readfirstlane'd so offsets/index-chunks compile to scalar loads and row
// loads use SGPR base + constant lane offset.
template <int CHUNK, int SPW>
__global__ __launch_bounds__(256) void gather_pad(const unsigned* __restrict__ src,
                                                  const int* __restrict__ offs,
                                                  const int* __restrict__ nbr,
                                                  const float* __restrict__ scale,
                                                  unsigned* __restrict__ dst,
                                                  unsigned* __restrict__ ckpt,
                                                  int nseg) {
    int wv = __builtin_amdgcn_readfirstlane(blockIdx.x * 4 + (threadIdx.x >> 6));
    int lane = threadIdx.x & 63;
    int seg0 = wv * SPW;
    if (seg0 >= nseg) return;
    int p = offs[seg0];
#pragma unroll
    for (int i = 0; i < SPW; ++i) {
        int s = seg0 + i;
        int pend = offs[s + 1];
        float ax = 0.f, ay = 0.f;
        while (p < pend) {
            int4 c0 = *(const int4*)(nbr + p);
            unsigned v0 = src[(size_t)c0.x * 64 + lane];
            unsigned v1 = src[(size_t)c0.y * 64 + lane];
            unsigned v2 = src[(size_t)c0.z * 64 + lane];
            unsigned v3 = src[(size_t)c0.w * 64 + lane];
            if (CHUNK == 8) {
                int4 c1 = *(const int4*)(nbr + p + 4);
                unsigned v4 = src[(size_t)c1.x * 64 + lane];
                unsigned v5 = src[(size_t)c1.y * 64 + lane];
                unsigned v6 = src[(size_t)c1.z * 64 + lane];
                unsigned v7 = src[(size_t)c1.w * 64 + lane];
                ax += bflo(v0); ay += bfhi(v0);
                ax += bflo(v1); ay += bfhi(v1);
                ax += bflo(v2); ay += bfhi(v2);
                ax += bflo(v3); ay += bfhi(v3);
                ax += bflo(v4); ay += bfhi(v4);
                ax += bflo(v5); ay += bfhi(v5);
                ax += bflo(v6); ay += bfhi(v6);
                ax += bflo(v7); ay += bfhi(v7);
            } else {
                ax += bflo(v0); ay += bfhi(v0);
                ax += bflo(v1); ay += bfhi(v1);
                ax += bflo(v2); ay += bfhi(v2);
                ax += bflo(v3); ay += bfhi(v3);
            }
            p += CHUNK;
        }
        float sc = scale[s];
        unsigned pk = pack_bf2(ax * sc, ay * sc);
        dst[(size_t)s * 64 + lane] = pk;
        if (ckpt) ckpt[(size_t)s * 1536 + lane] = pk;
    }
}

// ---------------- final wavelet combine + relu split ----------------
// Checkpoints are bf16(inv_v * L) at out dword offset v*1536 + slot*256 + [0,64);
// recover L = ckpt * deg_v. Block = 256 threads = 8 vertices; read all, sync, write.
__global__ __launch_bounds__(256) void wavelet_out(const float* __restrict__ X,
                                                   const int* __restrict__ deg_v,
                                                   float* __restrict__ out) {
    int tid = blockIdx.x * 256 + threadIdx.x;
    int v = tid >> 5;
    int f4 = (tid & 31) * 4;
    float* row = out + (size_t)v * 1536;
    const unsigned* rowu = (const unsigned*)row;
    float degf = (float)deg_v[v];
    float4 L0v = *(const float4*)(X + (size_t)v * FEAT + f4);
    float l0[4] = {L0v.x, L0v.y, L0v.z, L0v.w};
    float L[5][4];
#pragma unroll
    for (int sl = 0; sl < 5; ++sl) {
        unsigned d0 = rowu[(sl + 1) * 256 + (f4 >> 1)];
        unsigned d1 = rowu[(sl + 1) * 256 + (f4 >> 1) + 1];
        L[sl][0] = bflo(d0) * degf;
        L[sl][1] = bfhi(d0) * degf;
        L[sl][2] = bflo(d1) * degf;
        L[sl][3] = bfhi(d1) * degf;
    }
    float wv[6][4];
#pragma unroll
    for (int j = 0; j < 4; ++j) {
        wv[0][j] = l0[j] - L[0][j];
        wv[1][j] = L[0][j] - L[1][j];
        wv[2][j] = L[1][j] - L[2][j];
        wv[3][j] = L[2][j] - L[3][j];
        wv[4][j] = L[3][j] - L[4][j];
        wv[5][j] = L[4][j];
    }
    __syncthreads();
#pragma unroll
    for (int r = 0; r < 6; ++r) {
        float4 pp, mm;
        pp.x = fmaxf(wv[r][0], 0.f); mm.x = fmaxf(-wv[r][0], 0.f);
        pp.y = fmaxf(wv[r][1], 0.f); mm.y = fmaxf(-wv[r][1], 0.f);
        pp.z = fmaxf(wv[r][2], 0.f); mm.z = fmaxf(-wv[r][2], 0.f);
        pp.w = fmaxf(wv[r][3], 0.f); mm.w = fmaxf(-wv[r][3], 0.f);
        *(float4*)(row + r * 256 + f4) = pp;
        *(float4*)(row + r * 256 + 128 + f4) = mm;
    }
}

// ---------------- launch ----------------

extern "C" void kernel_launch(void* const* d_in, const int* in_sizes, int n_in,
                              void* d_out, int out_size, void* d_ws, size_t ws_size,
                              hipStream_t stream) {
    const float* X = (const float*)d_in[0];
    const int* vids = (const int*)d_in[1];
    const int* eids = (const int*)d_in[2];
    const int NNZ = in_sizes[1];         // 1048576
    const int V = in_sizes[0] / FEAT;    // 65536
    const int E = 16384;                 // num_e
    float* out = (float*)d_out;

    const int NBRE_CAP = NNZ + E * 8;    // edge lists, CHUNK=8 padding
    const int NBRV_CAP = NNZ + V * 4;    // vertex lists, CHUNK=4 padding

    char* w = (char*)d_ws;
    size_t o = 0;
    auto take = [&](size_t bytes) {
        void* p = (void*)(w + o);
        o = (o + bytes + 255) & ~(size_t)255;
        return p;
    };
    int* deg_v = (int*)take((size_t)(V + E) * 4);  // deg_v, deg_e contiguous
    int* deg_e = deg_v + V;
    int* off_e = (int*)take((size_t)(E + 1) * 4);
    int* off_v = (int*)take((size_t)(V + 1) * 4);
    int* cur_e = (int*)take((size_t)E * 4);
    int* cur_v = (int*)take((size_t)V * 4);
    float* inv_e = (float*)take((size_t)E * 4);
    float* inv_v = (float*)take((size_t)V * 4);
    int* e_nbr_v = (int*)take((size_t)NBRE_CAP * 4);       // edge segs -> vertex rows
    int* v_nbr_e = (int*)take((size_t)NBRV_CAP * 4);       // vertex segs -> edge rows
    unsigned* xs = (unsigned*)take((size_t)(V + 1) * 64 * 4);  // bf16x2 [V+1][64]
    unsigned* es = (unsigned*)take((size_t)(E + 1) * 64 * 4);  // bf16x2 [E+1][64]
    (void)ws_size;
    (void)n_in;
    (void)out_size;

    // 1) degrees
    hipMemsetAsync(deg_v, 0, (size_t)(V + E) * 4, stream);
    count_deg<<<(NNZ + 255) / 256, 256, 0, stream>>>(vids, eids, deg_v, deg_e, NNZ);

    // 2) padded offsets + cursors + inverse true degrees
    scan_pad<16384, 1024, 8><<<1, 1024, 0, stream>>>(deg_e, off_e, cur_e, inv_e);
    scan_pad<65536, 1024, 4><<<1, 1024, 0, stream>>>(deg_v, off_v, cur_v, inv_v);

    // 3) dummy-fill padded lists (dummy -> zero row), zero dummy rows
    {
        int mx = NBRV_CAP > NBRE_CAP ? NBRV_CAP : NBRE_CAP;
        init_pad<<<(mx + 255) / 256, 256, 0, stream>>>(e_nbr_v, NBRE_CAP, V,
                                                       v_nbr_e, NBRV_CAP, E,
                                                       xs + (size_t)V * 64,
                                                       es + (size_t)E * 64);
    }

    // 4) adjacency lists (real entries; padded tails keep dummy)
    fill_csr<<<(NNZ + 255) / 256, 256, 0, stream>>>(vids, eids, cur_v, cur_e, v_nbr_e, e_nbr_v, NNZ);

    // 5) xs = bf16(X * inv_v)
    prescale<<<V * 64 / 256, 256, 0, stream>>>(X, inv_v, xs);

    // 6) 16 diffusion steps; checkpoints k in {1,2,4,8,16} also write the packed
    //    bf16 scaled level into out[v, slot, 0:64 dwords] (recovered by *deg_v).
    for (int k = 1; k <= 16; ++k) {
        gather_pad<8, 1><<<E / 4, 256, 0, stream>>>(xs, off_e, e_nbr_v, inv_e, es, nullptr, E);
        unsigned* ck = nullptr;
        if (k == 1) ck = (unsigned*)out + 1 * 256;
        else if (k == 2) ck = (unsigned*)out + 2 * 256;
        else if (k == 4) ck = (unsigned*)out + 3 * 256;
        else if (k == 8) ck = (unsigned*)out + 4 * 256;
        else if (k == 16) ck = (unsigned*)out + 5 * 256;
        gather_pad<4, 4><<<V / 16, 256, 0, stream>>>(es, off_v, v_nbr_e, inv_v, xs, ck, V);
    }

    // 7) wavelet combine + relu split, in place over out
    wavelet_out<<<V * 32 / 256, 256, 0, stream>>>(X, deg_v, out);
}